// Round 16
// baseline (210.340 us; speedup 1.0000x reference)
//
#include <hip/hip_runtime.h>
#include <hip/hip_bf16.h>
#include <stdint.h>

#define R_ 8
#define N_ 8192
#define D_ 2048
#define A_ 128
#define J_ 1024          // R_*A_
#define LN_EPS 1e-5f

typedef __attribute__((ext_vector_type(8))) short bf16x8;   // 8 bf16 in 4 VGPRs
typedef __attribute__((ext_vector_type(4))) float f32x4;

__device__ inline ushort f2bf(float f) {
    union { float f; uint32_t u; } v; v.f = f;
    uint32_t u = v.u;
    return (ushort)((u + 0x7fffu + ((u >> 16) & 1u)) >> 16);   // RNE
}
__device__ inline float bf2f(ushort u) {
    union { uint32_t u; float f; } v; v.u = ((uint32_t)u) << 16;
    return v.f;
}

// ---------------------------------------------------------------------------
// k_prep: blocks [0,N_)   : row-LN stats of x -> xhat bf16 (shared by routers)
//         blocks [N_,N_+J_): weight-LN column j -> Bt bf16 (K-major) + cvec
// ---------------------------------------------------------------------------
__global__ __launch_bounds__(256) void k_prep(
    const float* __restrict__ x,
    const float* __restrict__ W,
    const float* __restrict__ ln_w,
    const float* __restrict__ ln_b,
    const float* __restrict__ rw_w,
    const float* __restrict__ rw_b,
    const float* __restrict__ rbias,
    ushort* __restrict__ xhat,
    ushort* __restrict__ Bt,
    float* __restrict__ cvec)
{
    __shared__ float sm[16];
    const int t = threadIdx.x;

    if (blockIdx.x < N_) {
        const int n = blockIdx.x;
        const float* xr = x + (size_t)n * D_;
        float4 v0 = *(const float4*)(xr + t * 4);
        float4 v1 = *(const float4*)(xr + 1024 + t * 4);
        float s  = v0.x + v0.y + v0.z + v0.w + v1.x + v1.y + v1.z + v1.w;
        float sq = v0.x*v0.x + v0.y*v0.y + v0.z*v0.z + v0.w*v0.w
                 + v1.x*v1.x + v1.y*v1.y + v1.z*v1.z + v1.w*v1.w;
        #pragma unroll
        for (int o = 32; o > 0; o >>= 1) {
            s  += __shfl_xor(s,  o, 64);
            sq += __shfl_xor(sq, o, 64);
        }
        if ((t & 63) == 0) { sm[t >> 6] = s; sm[8 + (t >> 6)] = sq; }
        __syncthreads();
        s  = sm[0] + sm[1] + sm[2] + sm[3];
        sq = sm[8] + sm[9] + sm[10] + sm[11];
        const float mean = s * (1.0f / D_);
        const float var  = sq * (1.0f / D_) - mean * mean;
        const float rstd = rsqrtf(var + LN_EPS);

        ushort4 p0 = make_ushort4(f2bf((v0.x - mean) * rstd), f2bf((v0.y - mean) * rstd),
                                  f2bf((v0.z - mean) * rstd), f2bf((v0.w - mean) * rstd));
        ushort4 p1 = make_ushort4(f2bf((v1.x - mean) * rstd), f2bf((v1.y - mean) * rstd),
                                  f2bf((v1.z - mean) * rstd), f2bf((v1.w - mean) * rstd));
        *(ushort4*)(xhat + (size_t)n * D_ + t * 4)        = p0;
        *(ushort4*)(xhat + (size_t)n * D_ + 1024 + t * 4) = p1;
    } else {
        const int j = blockIdx.x - N_;
        const int r = j >> 7, a = j & 127;
        const float* Wc = W + (size_t)r * D_ * A_ + a;

        float vals[8];
        float s = 0.f, sq = 0.f;
        #pragma unroll
        for (int k = 0; k < 8; ++k) {
            float v = Wc[(size_t)(t + k * 256) * A_];
            vals[k] = v; s += v; sq += v * v;
        }
        #pragma unroll
        for (int o = 32; o > 0; o >>= 1) {
            s  += __shfl_xor(s,  o, 64);
            sq += __shfl_xor(sq, o, 64);
        }
        if ((t & 63) == 0) { sm[t >> 6] = s; sm[8 + (t >> 6)] = sq; }
        __syncthreads();
        s  = sm[0] + sm[1] + sm[2] + sm[3];
        sq = sm[8] + sm[9] + sm[10] + sm[11];
        const float mean = s * (1.0f / D_);
        const float var  = sq * (1.0f / D_) - mean * mean;
        const float rstd = rsqrtf(var + LN_EPS);

        float cp = 0.f;
        #pragma unroll
        for (int k = 0; k < 8; ++k) {
            const int d = t + k * 256;
            const float nv = (vals[k] - mean) * rstd * rw_w[(size_t)r * D_ + d]
                           + rw_b[(size_t)r * D_ + d];
            Bt[(size_t)j * D_ + d] = f2bf(ln_w[(size_t)r * D_ + d] * nv);
            cp += ln_b[(size_t)r * D_ + d] * nv;
        }
        __syncthreads();   // sm reuse
        #pragma unroll
        for (int o = 32; o > 0; o >>= 1) cp += __shfl_xor(cp, o, 64);
        if ((t & 63) == 0) sm[t >> 6] = cp;
        __syncthreads();
        if (t == 0) cvec[j] = sm[0] + sm[1] + sm[2] + sm[3] + rbias[(size_t)r * A_ + a];
    }
}

// ---------------------------------------------------------------------------
// k_fused (R16): R15 GEMM loop (BK=64, T2 swizzle) + FULL-ROW contiguous
//   new_x writes. Per iteration the block writes 2 COMPLETE 8-KB rows
//   (2kt, 2kt+1): wave w handles row 2kt+(w>>1), half (w&1); each NT store
//   instruction = 64 lanes x 16 B = 1 KB contiguous; the block's 512 KiB
//   region is swept sequentially (fillBuffer's pattern) instead of R15's
//   256 B-per-row scatter. Source = xhat from global (L3-hot; 512 B
//   contiguous ushort4 loads issued before the staging barrier so their
//   latency hides under the staging drain). LN params in 32 VGPRs.
//   decode r = bid&7 (router == XCD, Bt[r] L2-resident). LDS 24 KB.
// ---------------------------------------------------------------------------
__global__ __launch_bounds__(256) void k_fused(
    const ushort* __restrict__ Xh,
    const ushort* __restrict__ Bt,
    const float* __restrict__ cvec,
    const float* __restrict__ ln_w,
    const float* __restrict__ ln_b,
    float* __restrict__ new_x,
    float* __restrict__ logits,
    float* __restrict__ probs)
{
    __shared__ __attribute__((aligned(16))) ushort As[64 * 64];    // 8 KB
    __shared__ __attribute__((aligned(16))) ushort Bs[128 * 64];   // 16 KB

    const int t    = threadIdx.x;
    const int lane = t & 63;
    const int w    = t >> 6;             // wave 0..3, MFMA rows w*16..w*16+15
    const int r    = blockIdx.x & 7;     // router == XCD
    const int mt   = blockIdx.x >> 3;    // m-tile 0..127
    const int m0   = mt * 64;
    const int j0   = r * 128;

    // write-role geometry: wave w -> row-parity (w>>1), col-half (w&1);
    // per store s: cols cbase + s*256 .. (1 KB contiguous per instruction)
    const int cbase = (w & 1) * 1024 + lane * 4;
    f32x4 lwv[4], lbv[4];
    #pragma unroll
    for (int s = 0; s < 4; ++s) {
        lwv[s] = *(const f32x4*)(ln_w + (size_t)r * D_ + cbase + s * 256);
        lbv[s] = *(const f32x4*)(ln_b + (size_t)r * D_ + cbase + s * 256);
    }

    f32x4 acc[8];
    #pragma unroll
    for (int jf = 0; jf < 8; ++jf) acc[jf] = (f32x4){0.f, 0.f, 0.f, 0.f};

    float* nx_base = new_x + ((size_t)r * N_ + m0) * D_;

    for (int kt = 0; kt < 32; ++kt) {
        __syncthreads();                 // prev iter's LDS reads done
        // stage A: 512 chunks (2/thread); LDS (row,slot) <- global kc=slot^(row&7)
        #pragma unroll
        for (int c = 0; c < 2; ++c) {
            const int q    = t + c * 256;    // 0..511
            const int row  = q >> 3;         // 0..63
            const int slot = q & 7;
            const int kc   = slot ^ (row & 7);
            const ushort* gA = Xh + (size_t)(m0 + row) * D_ + kt * 64 + kc * 8;
            __builtin_amdgcn_global_load_lds(
                (const __attribute__((address_space(1))) void*)gA,
                (__attribute__((address_space(3))) void*)(&As[q * 8]), 16, 0, 0);
        }
        // stage B: 1024 chunks (4/thread)
        #pragma unroll
        for (int c = 0; c < 4; ++c) {
            const int q    = t + c * 256;    // 0..1023
            const int row  = q >> 3;         // 0..127
            const int slot = q & 7;
            const int kc   = slot ^ (row & 7);
            const ushort* gB = Bt + (size_t)(j0 + row) * D_ + kt * 64 + kc * 8;
            __builtin_amdgcn_global_load_lds(
                (const __attribute__((address_space(1))) void*)gB,
                (__attribute__((address_space(3))) void*)(&Bs[q * 8]), 16, 0, 0);
        }

        // issue xhat row reads for this iter's 2 full rows (512 B contiguous
        // per instruction; latency overlaps the staging drain below)
        const int wrow = 2 * kt + (w >> 1);              // 0..63
        const ushort* xs = Xh + (size_t)(m0 + wrow) * D_ + cbase;
        ushort4 hb[4];
        #pragma unroll
        for (int s = 0; s < 4; ++s) hb[s] = *(const ushort4*)(xs + s * 256);

        __syncthreads();                 // staging (+ row reads) complete

        // full-row new_x writes: 4 x 1 KB contiguous NT stores per wave
        {
            float* nd = nx_base + (size_t)wrow * D_ + cbase;
            #pragma unroll
            for (int s = 0; s < 4; ++s) {
                f32x4 o;
                o[0] = bf2f(hb[s].x) * lwv[s][0] + lbv[s][0];
                o[1] = bf2f(hb[s].y) * lwv[s][1] + lbv[s][1];
                o[2] = bf2f(hb[s].z) * lwv[s][2] + lbv[s][2];
                o[3] = bf2f(hb[s].w) * lwv[s][3] + lbv[s][3];
                __builtin_nontemporal_store(o, (f32x4*)(nd + s * 256));
            }
        }

        // MFMA: wave w rows w*16..+15; 2 k-frags x 8 j-frags, swizzled reads
        #pragma unroll
        for (int kf = 0; kf < 2; ++kf) {
            const int slot  = (lane >> 4) + 4 * kf;
            const int pslot = slot ^ (lane & 7);
            const bf16x8 afr = *(const bf16x8*)(&As[(w * 16 + (lane & 15)) * 64
                                                    + pslot * 8]);
            #pragma unroll
            for (int jf = 0; jf < 8; ++jf) {
                const bf16x8 bfr = *(const bf16x8*)(&Bs[(jf * 16 + (lane & 15)) * 64
                                                        + pslot * 8]);
                acc[jf] = __builtin_amdgcn_mfma_f32_16x16x32_bf16(afr, bfr, acc[jf], 0, 0, 0);
            }
        }
    }

    // Epilogue: bias + row softmax (j-range == router r's full A=128).
    // C/D layout: col = lane&15, row = (lane>>4)*4 + reg.
    float cv[8];
    #pragma unroll
    for (int jf = 0; jf < 8; ++jf) cv[jf] = cvec[j0 + jf * 16 + (lane & 15)];

    #pragma unroll
    for (int reg = 0; reg < 4; ++reg) {
        const int row = m0 + w * 16 + (lane >> 4) * 4 + reg;
        float v[8], e[8];
        float mx = -3.4e38f;
        #pragma unroll
        for (int jf = 0; jf < 8; ++jf) {
            v[jf] = acc[jf][reg] + cv[jf];
            mx = fmaxf(mx, v[jf]);
        }
        #pragma unroll
        for (int o = 8; o > 0; o >>= 1) mx = fmaxf(mx, __shfl_xor(mx, o, 64));
        float ssum = 0.f;
        #pragma unroll
        for (int jf = 0; jf < 8; ++jf) { e[jf] = __expf(v[jf] - mx); ssum += e[jf]; }
        #pragma unroll
        for (int o = 8; o > 0; o >>= 1) ssum += __shfl_xor(ssum, o, 64);
        const float inv = 1.0f / ssum;
        float* lrow = logits + ((size_t)r * N_ + row) * A_;
        float* prow = probs  + ((size_t)r * N_ + row) * A_;
        #pragma unroll
        for (int jf = 0; jf < 8; ++jf) {
            const int aa = jf * 16 + (lane & 15);
            __builtin_nontemporal_store(v[jf], lrow + aa);
            __builtin_nontemporal_store(e[jf] * inv, prow + aa);
        }
    }
}

// ---------------------------------------------------------------------------
extern "C" void kernel_launch(void* const* d_in, const int* in_sizes, int n_in,
                              void* d_out, int out_size, void* d_ws, size_t ws_size,
                              hipStream_t stream)
{
    const float* x     = (const float*)d_in[0];
    const float* ln_w  = (const float*)d_in[1];
    const float* ln_b  = (const float*)d_in[2];
    const float* W     = (const float*)d_in[3];
    const float* rw_w  = (const float*)d_in[4];
    const float* rw_b  = (const float*)d_in[5];
    const float* rbias = (const float*)d_in[6];

    float* out    = (float*)d_out;
    float* new_x  = out;                                   // [R,N,D]
    float* logits = out + (size_t)R_ * N_ * D_;            // [R,N,A]
    float* probs  = logits + (size_t)R_ * N_ * A_;         // [R,N,A]

    // ws: xhat bf16 [N][D] (32 MiB) | Bt bf16 [J][D] (4 MiB) | cvec f32 [J]
    ushort* xhat = (ushort*)d_ws;
    ushort* Btp  = (ushort*)((char*)d_ws + (size_t)N_ * D_ * 2);
    float*  cvec = (float*)((char*)d_ws + (size_t)N_ * D_ * 2 + (size_t)J_ * D_ * 2);

    hipLaunchKernelGGL(k_prep, dim3(N_ + J_), dim3(256), 0, stream,
                       x, W, ln_w, ln_b, rw_w, rw_b, rbias, xhat, Btp, cvec);
    hipLaunchKernelGGL(k_fused, dim3(J_), dim3(256), 0, stream,
                       xhat, Btp, cvec, ln_w, ln_b, new_x, logits, probs);
}

// Round 17
// 186.785 us; speedup vs baseline: 1.1261x; 1.1261x over previous
//
#include <hip/hip_runtime.h>
#include <hip/hip_bf16.h>
#include <stdint.h>

#define R_ 8
#define N_ 8192
#define D_ 2048
#define A_ 128
#define J_ 1024          // R_*A_
#define LN_EPS 1e-5f

typedef __attribute__((ext_vector_type(8))) short bf16x8;   // 8 bf16 in 4 VGPRs
typedef __attribute__((ext_vector_type(4))) float f32x4;

__device__ inline ushort f2bf(float f) {
    union { float f; uint32_t u; } v; v.f = f;
    uint32_t u = v.u;
    return (ushort)((u + 0x7fffu + ((u >> 16) & 1u)) >> 16);   // RNE
}
__device__ inline float bf2f(ushort u) {
    union { uint32_t u; float f; } v; v.u = ((uint32_t)u) << 16;
    return v.f;
}

// ---------------------------------------------------------------------------
// k_prep: 9216 blocks in groups of 9: 8 x-LN blocks + 1 W-LN block.
//   Interleaving spreads the latency-bound W-column blocks (strided reads)
//   through the BW-bound x stream instead of running them as a serial tail.
// ---------------------------------------------------------------------------
__global__ __launch_bounds__(256) void k_prep(
    const float* __restrict__ x,
    const float* __restrict__ W,
    const float* __restrict__ ln_w,
    const float* __restrict__ ln_b,
    const float* __restrict__ rw_w,
    const float* __restrict__ rw_b,
    const float* __restrict__ rbias,
    ushort* __restrict__ xhat,
    ushort* __restrict__ Bt,
    float* __restrict__ cvec)
{
    __shared__ float sm[16];
    const int t = threadIdx.x;
    const int g = blockIdx.x / 9;
    const int i = blockIdx.x % 9;

    if (i < 8) {
        const int n = g * 8 + i;
        const float* xr = x + (size_t)n * D_;
        float4 v0 = *(const float4*)(xr + t * 4);
        float4 v1 = *(const float4*)(xr + 1024 + t * 4);
        float s  = v0.x + v0.y + v0.z + v0.w + v1.x + v1.y + v1.z + v1.w;
        float sq = v0.x*v0.x + v0.y*v0.y + v0.z*v0.z + v0.w*v0.w
                 + v1.x*v1.x + v1.y*v1.y + v1.z*v1.z + v1.w*v1.w;
        #pragma unroll
        for (int o = 32; o > 0; o >>= 1) {
            s  += __shfl_xor(s,  o, 64);
            sq += __shfl_xor(sq, o, 64);
        }
        if ((t & 63) == 0) { sm[t >> 6] = s; sm[8 + (t >> 6)] = sq; }
        __syncthreads();
        s  = sm[0] + sm[1] + sm[2] + sm[3];
        sq = sm[8] + sm[9] + sm[10] + sm[11];
        const float mean = s * (1.0f / D_);
        const float var  = sq * (1.0f / D_) - mean * mean;
        const float rstd = rsqrtf(var + LN_EPS);

        ushort4 p0 = make_ushort4(f2bf((v0.x - mean) * rstd), f2bf((v0.y - mean) * rstd),
                                  f2bf((v0.z - mean) * rstd), f2bf((v0.w - mean) * rstd));
        ushort4 p1 = make_ushort4(f2bf((v1.x - mean) * rstd), f2bf((v1.y - mean) * rstd),
                                  f2bf((v1.z - mean) * rstd), f2bf((v1.w - mean) * rstd));
        *(ushort4*)(xhat + (size_t)n * D_ + t * 4)        = p0;
        *(ushort4*)(xhat + (size_t)n * D_ + 1024 + t * 4) = p1;
    } else {
        const int j = g;
        const int r = j >> 7, a = j & 127;
        const float* Wc = W + (size_t)r * D_ * A_ + a;

        float vals[8];
        float s = 0.f, sq = 0.f;
        #pragma unroll
        for (int k = 0; k < 8; ++k) {
            float v = Wc[(size_t)(t + k * 256) * A_];
            vals[k] = v; s += v; sq += v * v;
        }
        #pragma unroll
        for (int o = 32; o > 0; o >>= 1) {
            s  += __shfl_xor(s,  o, 64);
            sq += __shfl_xor(sq, o, 64);
        }
        if ((t & 63) == 0) { sm[t >> 6] = s; sm[8 + (t >> 6)] = sq; }
        __syncthreads();
        s  = sm[0] + sm[1] + sm[2] + sm[3];
        sq = sm[8] + sm[9] + sm[10] + sm[11];
        const float mean = s * (1.0f / D_);
        const float var  = sq * (1.0f / D_) - mean * mean;
        const float rstd = rsqrtf(var + LN_EPS);

        float cp = 0.f;
        #pragma unroll
        for (int k = 0; k < 8; ++k) {
            const int d = t + k * 256;
            const float nv = (vals[k] - mean) * rstd * rw_w[(size_t)r * D_ + d]
                           + rw_b[(size_t)r * D_ + d];
            Bt[(size_t)j * D_ + d] = f2bf(ln_w[(size_t)r * D_ + d] * nv);
            cp += ln_b[(size_t)r * D_ + d] * nv;
        }
        __syncthreads();   // sm reuse
        #pragma unroll
        for (int o = 32; o > 0; o >>= 1) cp += __shfl_xor(cp, o, 64);
        if ((t & 63) == 0) sm[t >> 6] = cp;
        __syncthreads();
        if (t == 0) cvec[j] = sm[0] + sm[1] + sm[2] + sm[3] + rbias[(size_t)r * A_ + a];
    }
}

// ---------------------------------------------------------------------------
// k_fused (R17): R15's winning loop (BK=64, T2 swizzle, slab-from-LDS NT
//   writes) UNCHANGED. New epilogue: per reg-group, transpose v/p through
//   the freed As/Bs LDS (16x128 f32 each, exact fit) and emit 512-B
//   contiguous NT stores (16 lanes per output row) instead of 64-B scatter.
//   decode r = bid&7 (router == XCD, Bt[r] L2-resident).
// ---------------------------------------------------------------------------
__global__ __launch_bounds__(256) void k_fused(
    const ushort* __restrict__ Xh,
    const ushort* __restrict__ Bt,
    const float* __restrict__ cvec,
    const float* __restrict__ ln_w,
    const float* __restrict__ ln_b,
    float* __restrict__ new_x,
    float* __restrict__ logits,
    float* __restrict__ probs)
{
    __shared__ __attribute__((aligned(16))) ushort As[64 * 64];    // 8 KB
    __shared__ __attribute__((aligned(16))) ushort Bs[128 * 64];   // 16 KB
    __shared__ __attribute__((aligned(16))) ushort lwS[D_];        // 4 KB
    __shared__ __attribute__((aligned(16))) ushort lbS[D_];        // 4 KB

    const int t    = threadIdx.x;
    const int lane = t & 63;
    const int w    = t >> 6;             // wave 0..3, rows w*16..w*16+15
    const int r    = blockIdx.x & 7;     // router == XCD
    const int mt   = blockIdx.x >> 3;    // m-tile 0..127
    const int m0   = mt * 64;
    const int j0   = r * 128;

    // LN params as bf16 (gamma=1/beta=0: bf16-exact); 8 ushorts per thread
    {
        const float4 wa = ((const float4*)(ln_w + (size_t)r * D_))[2 * t];
        const float4 wb = ((const float4*)(ln_w + (size_t)r * D_))[2 * t + 1];
        const float4 ba = ((const float4*)(ln_b + (size_t)r * D_))[2 * t];
        const float4 bb = ((const float4*)(ln_b + (size_t)r * D_))[2 * t + 1];
        *(ushort4*)(&lwS[t * 8])     = make_ushort4(f2bf(wa.x), f2bf(wa.y), f2bf(wa.z), f2bf(wa.w));
        *(ushort4*)(&lwS[t * 8 + 4]) = make_ushort4(f2bf(wb.x), f2bf(wb.y), f2bf(wb.z), f2bf(wb.w));
        *(ushort4*)(&lbS[t * 8])     = make_ushort4(f2bf(ba.x), f2bf(ba.y), f2bf(ba.z), f2bf(ba.w));
        *(ushort4*)(&lbS[t * 8 + 4]) = make_ushort4(f2bf(bb.x), f2bf(bb.y), f2bf(bb.z), f2bf(bb.w));
    }

    f32x4 acc[8];
    #pragma unroll
    for (int jf = 0; jf < 8; ++jf) acc[jf] = (f32x4){0.f, 0.f, 0.f, 0.f};

    float* nx_base = new_x + ((size_t)r * N_ + m0) * D_;

    for (int kt = 0; kt < 32; ++kt) {
        __syncthreads();                 // prev iter's LDS reads done
        // stage A: 512 chunks (2/thread); LDS (row,slot) <- global kc=slot^(row&7)
        #pragma unroll
        for (int c = 0; c < 2; ++c) {
            const int q    = t + c * 256;    // 0..511
            const int row  = q >> 3;         // 0..63
            const int slot = q & 7;
            const int kc   = slot ^ (row & 7);
            const ushort* gA = Xh + (size_t)(m0 + row) * D_ + kt * 64 + kc * 8;
            __builtin_amdgcn_global_load_lds(
                (const __attribute__((address_space(1))) void*)gA,
                (__attribute__((address_space(3))) void*)(&As[q * 8]), 16, 0, 0);
        }
        // stage B: 1024 chunks (4/thread)
        #pragma unroll
        for (int c = 0; c < 4; ++c) {
            const int q    = t + c * 256;    // 0..1023
            const int row  = q >> 3;         // 0..127
            const int slot = q & 7;
            const int kc   = slot ^ (row & 7);
            const ushort* gB = Bt + (size_t)(j0 + row) * D_ + kt * 64 + kc * 8;
            __builtin_amdgcn_global_load_lds(
                (const __attribute__((address_space(1))) void*)gB,
                (__attribute__((address_space(3))) void*)(&Bs[q * 8]), 16, 0, 0);
        }
        __syncthreads();                 // staging complete

        // new_x slab: 64 rows x 64 cols fp32; 4 NT f32x4 per thread.
        const int kbase = kt * 64;
        #pragma unroll
        for (int c = 0; c < 4; ++c) {
            const int q     = t + c * 256;   // 0..1023
            const int row   = q >> 4;        // 0..63
            const int c4    = q & 15;        // 4-float group within 64 cols
            const int pslot = (c4 >> 1) ^ (row & 7);
            const ushort4 hb = *(const ushort4*)(&As[row * 64 + pslot * 8 + (c4 & 1) * 4]);
            const int d = kbase + c4 * 4;
            const ushort4 w4 = *(const ushort4*)(&lwS[d]);
            const ushort4 b4 = *(const ushort4*)(&lbS[d]);
            f32x4 o;
            o[0] = bf2f(hb.x) * bf2f(w4.x) + bf2f(b4.x);
            o[1] = bf2f(hb.y) * bf2f(w4.y) + bf2f(b4.y);
            o[2] = bf2f(hb.z) * bf2f(w4.z) + bf2f(b4.z);
            o[3] = bf2f(hb.w) * bf2f(w4.w) + bf2f(b4.w);
            __builtin_nontemporal_store(o, (f32x4*)(nx_base + (size_t)row * D_ + d));
        }

        // MFMA: wave w rows w*16..+15; 2 k-frags x 8 j-frags, swizzled reads
        #pragma unroll
        for (int kf = 0; kf < 2; ++kf) {
            const int slot  = (lane >> 4) + 4 * kf;
            const int pslot = slot ^ (lane & 7);
            const bf16x8 afr = *(const bf16x8*)(&As[(w * 16 + (lane & 15)) * 64
                                                    + pslot * 8]);
            #pragma unroll
            for (int jf = 0; jf < 8; ++jf) {
                const bf16x8 bfr = *(const bf16x8*)(&Bs[(jf * 16 + (lane & 15)) * 64
                                                        + pslot * 8]);
                acc[jf] = __builtin_amdgcn_mfma_f32_16x16x32_bf16(afr, bfr, acc[jf], 0, 0, 0);
            }
        }
    }

    // ---- Epilogue: bias + row softmax, transposed through LDS for
    //      512-B-contiguous NT stores. C/D: col=lane&15, row=(lane>>4)*4+reg.
    __syncthreads();                     // loop LDS reads complete; reuse As/Bs
    float* Lv = (float*)As;              // 16 x 128 f32 (8 KB)
    float* Lp = (float*)Bs;              // 16 x 128 f32 (8 KB)

    float cv[8];
    #pragma unroll
    for (int jf = 0; jf < 8; ++jf) cv[jf] = cvec[j0 + jf * 16 + (lane & 15)];

    const int oidx = t >> 4;             // 0..15 out-pass LDS row
    const int ocg  = t & 15;             // col group (8 floats = 32 B)

    #pragma unroll
    for (int reg = 0; reg < 4; ++reg) {
        float v[8], e[8];
        float mx = -3.4e38f;
        #pragma unroll
        for (int jf = 0; jf < 8; ++jf) {
            v[jf] = acc[jf][reg] + cv[jf];
            mx = fmaxf(mx, v[jf]);
        }
        #pragma unroll
        for (int o = 8; o > 0; o >>= 1) mx = fmaxf(mx, __shfl_xor(mx, o, 64));
        float ssum = 0.f;
        #pragma unroll
        for (int jf = 0; jf < 8; ++jf) { e[jf] = __expf(v[jf] - mx); ssum += e[jf]; }
        #pragma unroll
        for (int o = 8; o > 0; o >>= 1) ssum += __shfl_xor(ssum, o, 64);
        const float inv = 1.0f / ssum;

        const int lidx = w * 4 + (lane >> 4);        // LDS row 0..15
        #pragma unroll
        for (int jf = 0; jf < 8; ++jf) {
            Lv[lidx * 128 + jf * 16 + (lane & 15)] = v[jf];
            Lp[lidx * 128 + jf * 16 + (lane & 15)] = e[jf] * inv;
        }
        __syncthreads();
        {
            // LDS row oidx -> global row m0 + (oidx>>2)*16 + (oidx&3)*4 + reg
            const int grow = m0 + (oidx >> 2) * 16 + (oidx & 3) * 4 + reg;
            const f32x4 a0 = *(const f32x4*)(&Lv[oidx * 128 + ocg * 8]);
            const f32x4 a1 = *(const f32x4*)(&Lv[oidx * 128 + ocg * 8 + 4]);
            const f32x4 b0 = *(const f32x4*)(&Lp[oidx * 128 + ocg * 8]);
            const f32x4 b1 = *(const f32x4*)(&Lp[oidx * 128 + ocg * 8 + 4]);
            float* lrow = logits + ((size_t)r * N_ + grow) * A_ + ocg * 8;
            float* prow = probs  + ((size_t)r * N_ + grow) * A_ + ocg * 8;
            __builtin_nontemporal_store(a0, (f32x4*)lrow);
            __builtin_nontemporal_store(a1, (f32x4*)(lrow + 4));
            __builtin_nontemporal_store(b0, (f32x4*)prow);
            __builtin_nontemporal_store(b1, (f32x4*)(prow + 4));
        }
        __syncthreads();
    }
}

// ---------------------------------------------------------------------------
extern "C" void kernel_launch(void* const* d_in, const int* in_sizes, int n_in,
                              void* d_out, int out_size, void* d_ws, size_t ws_size,
                              hipStream_t stream)
{
    const float* x     = (const float*)d_in[0];
    const float* ln_w  = (const float*)d_in[1];
    const float* ln_b  = (const float*)d_in[2];
    const float* W     = (const float*)d_in[3];
    const float* rw_w  = (const float*)d_in[4];
    const float* rw_b  = (const float*)d_in[5];
    const float* rbias = (const float*)d_in[6];

    float* out    = (float*)d_out;
    float* new_x  = out;                                   // [R,N,D]
    float* logits = out + (size_t)R_ * N_ * D_;            // [R,N,A]
    float* probs  = logits + (size_t)R_ * N_ * A_;         // [R,N,A]

    // ws: xhat bf16 [N][D] (32 MiB) | Bt bf16 [J][D] (4 MiB) | cvec f32 [J]
    ushort* xhat = (ushort*)d_ws;
    ushort* Btp  = (ushort*)((char*)d_ws + (size_t)N_ * D_ * 2);
    float*  cvec = (float*)((char*)d_ws + (size_t)N_ * D_ * 2 + (size_t)J_ * D_ * 2);

    hipLaunchKernelGGL(k_prep, dim3(N_ + J_), dim3(256), 0, stream,
                       x, W, ln_w, ln_b, rw_w, rw_b, rbias, xhat, Btp, cvec);
    hipLaunchKernelGGL(k_fused, dim3(J_), dim3(256), 0, stream,
                       xhat, Btp, cvec, ln_w, ln_b, new_x, logits, probs);
}

// Round 18
// 163.825 us; speedup vs baseline: 1.2839x; 1.1401x over previous
//
#include <hip/hip_runtime.h>
#include <hip/hip_bf16.h>
#include <stdint.h>

#define R_ 8
#define N_ 8192
#define D_ 2048
#define A_ 128
#define J_ 1024          // R_*A_
#define LN_EPS 1e-5f

typedef __attribute__((ext_vector_type(8))) short bf16x8;   // 8 bf16 in 4 VGPRs
typedef __attribute__((ext_vector_type(4))) float f32x4;

__device__ inline ushort f2bf(float f) {
    union { float f; uint32_t u; } v; v.f = f;
    uint32_t u = v.u;
    return (ushort)((u + 0x7fffu + ((u >> 16) & 1u)) >> 16);   // RNE
}
__device__ inline float bf2f(ushort u) {
    union { uint32_t u; float f; } v; v.u = ((uint32_t)u) << 16;
    return v.f;
}

// ---------------------------------------------------------------------------
// k1 (k_lnx): 9216 blocks in groups of 9 (8 x-row blocks + 1 W-col block).
//   x-row block: row-LN stats (fp32 in registers) -> write xhat row (bf16,
//   plain store: k2 re-reads it, let it allocate in L2/L3) AND all 8
//   new_x rows DIRECTLY (fp32 from the un-rounded registers, NT stores,
//   1 KB contiguous per wave instruction). The 512 MiB stream is now a
//   PURE write stream — no GEMM staging competes with it (the 17-round
//   ledger shows mixed read+write streams run at ~3.8 of 6.7 TB/s).
//   W-col block: weight-LN of column j -> Bt (K-major bf16) + cvec.
// ---------------------------------------------------------------------------
__global__ __launch_bounds__(256) void k_lnx(
    const float* __restrict__ x,
    const float* __restrict__ W,
    const float* __restrict__ ln_w,
    const float* __restrict__ ln_b,
    const float* __restrict__ rw_w,
    const float* __restrict__ rw_b,
    const float* __restrict__ rbias,
    ushort* __restrict__ xhat,
    ushort* __restrict__ Bt,
    float* __restrict__ cvec,
    float* __restrict__ new_x)
{
    __shared__ float sm[16];
    const int t = threadIdx.x;
    const int g = blockIdx.x / 9;
    const int i = blockIdx.x % 9;

    if (i < 8) {
        const int n = g * 8 + i;
        const float* xr = x + (size_t)n * D_;
        float4 v0 = *(const float4*)(xr + t * 4);
        float4 v1 = *(const float4*)(xr + 1024 + t * 4);
        float s  = v0.x + v0.y + v0.z + v0.w + v1.x + v1.y + v1.z + v1.w;
        float sq = v0.x*v0.x + v0.y*v0.y + v0.z*v0.z + v0.w*v0.w
                 + v1.x*v1.x + v1.y*v1.y + v1.z*v1.z + v1.w*v1.w;
        #pragma unroll
        for (int o = 32; o > 0; o >>= 1) {
            s  += __shfl_xor(s,  o, 64);
            sq += __shfl_xor(sq, o, 64);
        }
        if ((t & 63) == 0) { sm[t >> 6] = s; sm[8 + (t >> 6)] = sq; }
        __syncthreads();
        s  = sm[0] + sm[1] + sm[2] + sm[3];
        sq = sm[8] + sm[9] + sm[10] + sm[11];
        const float mean = s * (1.0f / D_);
        const float var  = sq * (1.0f / D_) - mean * mean;
        const float rstd = rsqrtf(var + LN_EPS);

        // normalized row in fp32 registers
        float4 h0, h1;
        h0.x = (v0.x - mean) * rstd; h0.y = (v0.y - mean) * rstd;
        h0.z = (v0.z - mean) * rstd; h0.w = (v0.w - mean) * rstd;
        h1.x = (v1.x - mean) * rstd; h1.y = (v1.y - mean) * rstd;
        h1.z = (v1.z - mean) * rstd; h1.w = (v1.w - mean) * rstd;

        // xhat (bf16, plain store -> L2/L3 for k2's staging reads)
        ushort4 p0 = make_ushort4(f2bf(h0.x), f2bf(h0.y), f2bf(h0.z), f2bf(h0.w));
        ushort4 p1 = make_ushort4(f2bf(h1.x), f2bf(h1.y), f2bf(h1.z), f2bf(h1.w));
        *(ushort4*)(xhat + (size_t)n * D_ + t * 4)        = p0;
        *(ushort4*)(xhat + (size_t)n * D_ + 1024 + t * 4) = p1;

        // all 8 new_x rows: pure NT write stream, 1 KB contiguous per wave op
        #pragma unroll
        for (int r = 0; r < R_; ++r) {
            const float* wr = ln_w + (size_t)r * D_;
            const float* br = ln_b + (size_t)r * D_;
            const float4 w0 = *(const float4*)(wr + t * 4);
            const float4 b0 = *(const float4*)(br + t * 4);
            const float4 w1 = *(const float4*)(wr + 1024 + t * 4);
            const float4 b1 = *(const float4*)(br + 1024 + t * 4);
            f32x4 o0, o1;
            o0[0] = h0.x * w0.x + b0.x; o0[1] = h0.y * w0.y + b0.y;
            o0[2] = h0.z * w0.z + b0.z; o0[3] = h0.w * w0.w + b0.w;
            o1[0] = h1.x * w1.x + b1.x; o1[1] = h1.y * w1.y + b1.y;
            o1[2] = h1.z * w1.z + b1.z; o1[3] = h1.w * w1.w + b1.w;
            float* dst = new_x + ((size_t)r * N_ + n) * D_;
            __builtin_nontemporal_store(o0, (f32x4*)(dst + t * 4));
            __builtin_nontemporal_store(o1, (f32x4*)(dst + 1024 + t * 4));
        }
    } else {
        const int j = g;
        const int r = j >> 7, a = j & 127;
        const float* Wc = W + (size_t)r * D_ * A_ + a;

        float vals[8];
        float s = 0.f, sq = 0.f;
        #pragma unroll
        for (int k = 0; k < 8; ++k) {
            float v = Wc[(size_t)(t + k * 256) * A_];
            vals[k] = v; s += v; sq += v * v;
        }
        #pragma unroll
        for (int o = 32; o > 0; o >>= 1) {
            s  += __shfl_xor(s,  o, 64);
            sq += __shfl_xor(sq, o, 64);
        }
        if ((t & 63) == 0) { sm[t >> 6] = s; sm[8 + (t >> 6)] = sq; }
        __syncthreads();
        s  = sm[0] + sm[1] + sm[2] + sm[3];
        sq = sm[8] + sm[9] + sm[10] + sm[11];
        const float mean = s * (1.0f / D_);
        const float var  = sq * (1.0f / D_) - mean * mean;
        const float rstd = rsqrtf(var + LN_EPS);

        float cp = 0.f;
        #pragma unroll
        for (int k = 0; k < 8; ++k) {
            const int d = t + k * 256;
            const float nv = (vals[k] - mean) * rstd * rw_w[(size_t)r * D_ + d]
                           + rw_b[(size_t)r * D_ + d];
            Bt[(size_t)j * D_ + d] = f2bf(ln_w[(size_t)r * D_ + d] * nv);
            cp += ln_b[(size_t)r * D_ + d] * nv;
        }
        __syncthreads();   // sm reuse
        #pragma unroll
        for (int o = 32; o > 0; o >>= 1) cp += __shfl_xor(cp, o, 64);
        if ((t & 63) == 0) sm[t >> 6] = cp;
        __syncthreads();
        if (t == 0) cvec[j] = sm[0] + sm[1] + sm[2] + sm[3] + rbias[(size_t)r * A_ + a];
    }
}

// ---------------------------------------------------------------------------
// k2 (k_gemm): R15's GEMM loop (BK=64, T2 XOR-swizzle) WITHOUT the new_x
//   slab writes and param LDS -> 24 KB LDS, ~6 blocks/CU. Reads are L2
//   (Bt, router==XCD) / L3 (xhat) hot; only 64 MiB of output writes.
//   Epilogue: bias + row softmax, R15's NT scatter stores.
// ---------------------------------------------------------------------------
__global__ __launch_bounds__(256) void k_gemm(
    const ushort* __restrict__ Xh,
    const ushort* __restrict__ Bt,
    const float* __restrict__ cvec,
    float* __restrict__ logits,
    float* __restrict__ probs)
{
    __shared__ __attribute__((aligned(16))) ushort As[64 * 64];    // 8 KB
    __shared__ __attribute__((aligned(16))) ushort Bs[128 * 64];   // 16 KB

    const int t    = threadIdx.x;
    const int lane = t & 63;
    const int w    = t >> 6;             // wave 0..3, rows w*16..w*16+15
    const int r    = blockIdx.x & 7;     // router == XCD
    const int mt   = blockIdx.x >> 3;    // m-tile 0..127
    const int m0   = mt * 64;
    const int j0   = r * 128;

    f32x4 acc[8];
    #pragma unroll
    for (int jf = 0; jf < 8; ++jf) acc[jf] = (f32x4){0.f, 0.f, 0.f, 0.f};

    for (int kt = 0; kt < 32; ++kt) {
        __syncthreads();                 // prev iter's LDS reads done
        // stage A: 512 chunks (2/thread); LDS (row,slot) <- global kc=slot^(row&7)
        #pragma unroll
        for (int c = 0; c < 2; ++c) {
            const int q    = t + c * 256;    // 0..511
            const int row  = q >> 3;         // 0..63
            const int slot = q & 7;
            const int kc   = slot ^ (row & 7);
            const ushort* gA = Xh + (size_t)(m0 + row) * D_ + kt * 64 + kc * 8;
            __builtin_amdgcn_global_load_lds(
                (const __attribute__((address_space(1))) void*)gA,
                (__attribute__((address_space(3))) void*)(&As[q * 8]), 16, 0, 0);
        }
        // stage B: 1024 chunks (4/thread)
        #pragma unroll
        for (int c = 0; c < 4; ++c) {
            const int q    = t + c * 256;    // 0..1023
            const int row  = q >> 3;         // 0..127
            const int slot = q & 7;
            const int kc   = slot ^ (row & 7);
            const ushort* gB = Bt + (size_t)(j0 + row) * D_ + kt * 64 + kc * 8;
            __builtin_amdgcn_global_load_lds(
                (const __attribute__((address_space(1))) void*)gB,
                (__attribute__((address_space(3))) void*)(&Bs[q * 8]), 16, 0, 0);
        }
        __syncthreads();                 // staging complete

        // MFMA: wave w rows w*16..+15; 2 k-frags x 8 j-frags, swizzled reads
        #pragma unroll
        for (int kf = 0; kf < 2; ++kf) {
            const int slot  = (lane >> 4) + 4 * kf;
            const int pslot = slot ^ (lane & 7);
            const bf16x8 afr = *(const bf16x8*)(&As[(w * 16 + (lane & 15)) * 64
                                                    + pslot * 8]);
            #pragma unroll
            for (int jf = 0; jf < 8; ++jf) {
                const bf16x8 bfr = *(const bf16x8*)(&Bs[(jf * 16 + (lane & 15)) * 64
                                                        + pslot * 8]);
                acc[jf] = __builtin_amdgcn_mfma_f32_16x16x32_bf16(afr, bfr, acc[jf], 0, 0, 0);
            }
        }
    }

    // Epilogue: bias + row softmax (j-range == router r's full A=128).
    // C/D layout: col = lane&15, row = (lane>>4)*4 + reg.
    float cv[8];
    #pragma unroll
    for (int jf = 0; jf < 8; ++jf) cv[jf] = cvec[j0 + jf * 16 + (lane & 15)];

    #pragma unroll
    for (int reg = 0; reg < 4; ++reg) {
        const int row = m0 + w * 16 + (lane >> 4) * 4 + reg;
        float v[8], e[8];
        float mx = -3.4e38f;
        #pragma unroll
        for (int jf = 0; jf < 8; ++jf) {
            v[jf] = acc[jf][reg] + cv[jf];
            mx = fmaxf(mx, v[jf]);
        }
        #pragma unroll
        for (int o = 8; o > 0; o >>= 1) mx = fmaxf(mx, __shfl_xor(mx, o, 64));
        float ssum = 0.f;
        #pragma unroll
        for (int jf = 0; jf < 8; ++jf) { e[jf] = __expf(v[jf] - mx); ssum += e[jf]; }
        #pragma unroll
        for (int o = 8; o > 0; o >>= 1) ssum += __shfl_xor(ssum, o, 64);
        const float inv = 1.0f / ssum;
        float* lrow = logits + ((size_t)r * N_ + row) * A_;
        float* prow = probs  + ((size_t)r * N_ + row) * A_;
        #pragma unroll
        for (int jf = 0; jf < 8; ++jf) {
            const int aa = jf * 16 + (lane & 15);
            __builtin_nontemporal_store(v[jf], lrow + aa);
            __builtin_nontemporal_store(e[jf] * inv, prow + aa);
        }
    }
}

// ---------------------------------------------------------------------------
extern "C" void kernel_launch(void* const* d_in, const int* in_sizes, int n_in,
                              void* d_out, int out_size, void* d_ws, size_t ws_size,
                              hipStream_t stream)
{
    const float* x     = (const float*)d_in[0];
    const float* ln_w  = (const float*)d_in[1];
    const float* ln_b  = (const float*)d_in[2];
    const float* W     = (const float*)d_in[3];
    const float* rw_w  = (const float*)d_in[4];
    const float* rw_b  = (const float*)d_in[5];
    const float* rbias = (const float*)d_in[6];

    float* out    = (float*)d_out;
    float* new_x  = out;                                   // [R,N,D]
    float* logits = out + (size_t)R_ * N_ * D_;            // [R,N,A]
    float* probs  = logits + (size_t)R_ * N_ * A_;         // [R,N,A]

    // ws: xhat bf16 [N][D] (32 MiB) | Bt bf16 [J][D] (4 MiB) | cvec f32 [J]
    ushort* xhat = (ushort*)d_ws;
    ushort* Btp  = (ushort*)((char*)d_ws + (size_t)N_ * D_ * 2);
    float*  cvec = (float*)((char*)d_ws + (size_t)N_ * D_ * 2 + (size_t)J_ * D_ * 2);

    hipLaunchKernelGGL(k_lnx,  dim3(9 * J_), dim3(256), 0, stream,
                       x, W, ln_w, ln_b, rw_w, rw_b, rbias, xhat, Btp, cvec, new_x);
    hipLaunchKernelGGL(k_gemm, dim3(J_),     dim3(256), 0, stream,
                       xhat, Btp, cvec, logits, probs);
}